// Round 1
// baseline (242.930 us; speedup 1.0000x reference)
//
#include <hip/hip_runtime.h>
#include <math.h>

// Differentiable-rasterizer forward: scalar sum((render - ref)^2).
// B=2, V=512, F=768, S=256 per setup_inputs; B/V/F/S derived from in_sizes.
//
// Pipeline (all on `stream`):
//   k_pre    : per-vertex project to NDC (u,v,z) + tanh(textures)   [tiny]
//   k_face   : per-face affine coefficients for w0,w1,w2,invz + epilogue data
//   k_raster : per-pixel loop over all faces (argmax invz == argmin depth),
//              epilogue color + squared-diff, block partial sums (f64)
//   k_final  : reduce partials -> d_out[0] (f32)

__global__ void k_pre(const float* __restrict__ verts, const float* __restrict__ Kmat,
                      const float* __restrict__ Rmat, const float* __restrict__ tvec,
                      const float* __restrict__ texin,
                      float4* __restrict__ vout, float* __restrict__ texout,
                      int B, int V, int F, int S)
{
    int i = blockIdx.x * blockDim.x + threadIdx.x;
    int nv = B * V;
    int nt = F * 24;
    if (i < nv) {
        int b = i / V;
        const float* vp = verts + (size_t)i * 3;
        float vx = vp[0], vy = vp[1], vz = vp[2];
        const float* R  = Rmat + b * 9;
        const float* Kb = Kmat + b * 9;
        const float* tb = tvec + b * 3;
        float c0 = R[0]*vx + R[1]*vy + R[2]*vz + tb[0];
        float c1 = R[3]*vx + R[4]*vy + R[5]*vz + tb[1];
        float c2 = R[6]*vx + R[7]*vy + R[8]*vz + tb[2];
        float z  = c2;
        float zd = z + 1e-9f;
        float xh = c0 / zd;
        float yh = c1 / zd;
        float p0 = xh*Kb[0] + yh*Kb[1] + Kb[2];
        float p1 = xh*Kb[3] + yh*Kb[4] + Kb[5];
        float Sf = (float)S;
        float u = 2.0f * (p0 - 0.5f*Sf) / Sf;
        float v = 2.0f * ((Sf - p1) - 0.5f*Sf) / Sf;
        vout[i] = make_float4(u, v, z, 0.0f);
    }
    int j = i - nv;
    if (j >= 0 && j < nt) {
        texout[j] = tanhf(texin[j]);
    }
}

__global__ void k_face(const int* __restrict__ faces, const float4* __restrict__ vdat,
                       float4* __restrict__ finner, float4* __restrict__ fepi,
                       int B, int V, int F)
{
    int i = blockIdx.x * blockDim.x + threadIdx.x;
    if (i >= B * F) return;
    int b = i / F;
    const int* fp = faces + (size_t)i * 3;
    float4 p0 = vdat[b*V + fp[0]];
    float4 p1 = vdat[b*V + fp[1]];
    float4 p2 = vdat[b*V + fp[2]];
    float x0 = p0.x, y0 = p0.y, z0 = p0.z;
    float x1 = p1.x, y1 = p1.y, z1 = p1.z;
    float x2 = p2.x, y2 = p2.y, z2 = p2.z;
    float e1x = x1 - x0, e1y = y1 - y0;
    float e2x = x2 - x0, e2y = y2 - y0;
    float den = e1x*e2y - e2x*e1y;
    bool valid = fabsf(den) > 1e-8f;
    float dens = valid ? den : 1.0f;
    bool front = fminf(z0, fminf(z1, z2)) > 1e-9f;
    bool ok = valid && front;
    // w1 = ((px-x0)*e2y - (py-y0)*e2x)/dens   -> affine in (px,py)
    float A1 = e2y / dens, B1 = -e2x / dens;
    float C1 = -(x0*A1 + y0*B1);
    // w2 = (e1x*(py-y0) - e1y*(px-x0))/dens
    float A2 = -e1y / dens, B2 = e1x / dens;
    float C2 = -(x0*A2 + y0*B2);
    // w0 = 1 - w1 - w2
    float A0 = -A1 - A2, B0 = -B1 - B2, C0 = 1.0f - C1 - C2;
    // invz = w0/z0 + w1/z1 + w2/z2
    float rz0 = 1.0f/z0, rz1 = 1.0f/z1, rz2 = 1.0f/z2;
    float Az = A0*rz0 + A1*rz1 + A2*rz2;
    float Bz = B0*rz0 + B1*rz1 + B2*rz2;
    float Cz = C0*rz0 + C1*rz1 + C2*rz2;
    if (!ok) {  // fold valid&front: this face can never pass w0>=0
        A0 = B0 = 0.0f; C0 = -1.0f;
        A1 = B1 = C1 = 0.0f;
        A2 = B2 = C2 = 0.0f;
        Az = Bz = Cz = 0.0f;
    }
    finner[(size_t)i*3 + 0] = make_float4(A0, A1, A2, Az);
    finner[(size_t)i*3 + 1] = make_float4(B0, B1, B2, Bz);
    finner[(size_t)i*3 + 2] = make_float4(C0, C1, C2, Cz);
    // epilogue data (reference-exact recompute for chosen face)
    fepi[(size_t)i*3 + 0] = make_float4(x0, y0, z0, z1);
    fepi[(size_t)i*3 + 1] = make_float4(z2, e1x, e1y, e2x);
    fepi[(size_t)i*3 + 2] = make_float4(e2y, dens, 0.0f, 0.0f);
}

__global__ __launch_bounds__(256)
void k_raster(const float4* __restrict__ finner, const float4* __restrict__ fepi,
              const float* __restrict__ texd, const float* __restrict__ imref,
              double* __restrict__ partials, int B, int F, int S)
{
    int tid = threadIdx.x;
    int p   = blockIdx.x * 256 + tid;
    int SS  = S * S;
    int b   = p / SS;
    int rem = p - b * SS;
    int py  = rem / S;
    int px  = rem - py * S;
    float Sf  = (float)S;
    float pxf = (2.0f*px + 1.0f - Sf) / Sf;
    float pyf = (2.0f*py + 1.0f - Sf) / Sf;

    const float4* fd = finner + (size_t)b * F * 3;
    float best = 1e-9f;   // implements invz > EPS gate
    int   bidx = 0;
    for (int f = 0; f < F; ++f) {
        float4 Av = fd[(size_t)f*3 + 0];   // uniform address -> s_load
        float4 Bv = fd[(size_t)f*3 + 1];
        float4 Cv = fd[(size_t)f*3 + 2];
        float w0 = fmaf(pxf, Av.x, fmaf(pyf, Bv.x, Cv.x));
        float w1 = fmaf(pxf, Av.y, fmaf(pyf, Bv.y, Cv.y));
        float w2 = fmaf(pxf, Av.z, fmaf(pyf, Bv.z, Cv.z));
        float iz = fmaf(pxf, Av.w, fmaf(pyf, Bv.w, Cv.w));
        float mn = fminf(w0, fminf(w1, w2));
        bool upd = (mn >= 0.0f) && (iz > best);   // strict > keeps first == argmin semantics
        best = upd ? iz : best;
        bidx = upd ? f  : bidx;
    }
    bool hit = best > 1e-9f;

    // epilogue: reference-exact math on the selected face
    const float4* fe = fepi + (size_t)(b*F + bidx) * 3;
    float4 e0 = fe[0], e1 = fe[1], e2 = fe[2];
    float X0 = e0.x, Y0 = e0.y, Z0 = e0.z, Z1 = e0.w;
    float Z2 = e1.x, E1x = e1.y, E1y = e1.z, E2x = e1.w;
    float E2y = e2.x, D = e2.y;
    float dxp = pxf - X0, dyp = pyf - Y0;
    float W1 = (dxp*E2y - dyp*E2x) / D;
    float W2 = (E1x*dyp - E1y*dxp) / D;
    float W0 = 1.0f - W1 - W2;
    float q0 = W0 / Z0, q1 = W1 / Z1, q2 = W2 / Z2;
    float iz = fmaxf(q0 + q1 + q2, 1e-9f);
    float wp0 = fminf(fmaxf(q0 / iz, 0.0f), 1.0f);
    float wp1 = fminf(fmaxf(q1 / iz, 0.0f), 1.0f);
    float wp2 = fminf(fmaxf(q2 / iz, 0.0f), 1.0f);
    const float* T = texd + (size_t)bidx * 24;
    float hitf = hit ? 1.0f : 0.0f;
    float a0l = 1.0f - wp0, a0h = wp0;
    float a1l = 1.0f - wp1, a1h = wp1;
    float a2l = 1.0f - wp2, a2h = wp2;
    float s = 0.0f;
    #pragma unroll
    for (int c = 0; c < 3; ++c) {
        float col =
            a0l*(a1l*(a2l*T[0  + c] + a2h*T[3  + c]) + a1h*(a2l*T[6  + c] + a2h*T[9  + c])) +
            a0h*(a1l*(a2l*T[12 + c] + a2h*T[15 + c]) + a1h*(a2l*T[18 + c] + a2h*T[21 + c]));
        col *= hitf;
        float r = imref[(((size_t)b*3 + c)*S + py)*S + px];
        float d = col - r;
        s = fmaf(d, d, s);
    }

    // block reduction in f64 -> deterministic partial per block
    double acc = (double)s;
    #pragma unroll
    for (int off = 32; off > 0; off >>= 1)
        acc += __shfl_down(acc, off, 64);
    __shared__ double wsum[4];
    int lane = tid & 63, wid = tid >> 6;
    if (lane == 0) wsum[wid] = acc;
    __syncthreads();
    if (tid == 0) partials[blockIdx.x] = wsum[0] + wsum[1] + wsum[2] + wsum[3];
}

__global__ void k_final(const double* __restrict__ partials, float* __restrict__ out, int n)
{
    int tid = threadIdx.x;
    double a = 0.0;
    for (int i = tid; i < n; i += 256) a += partials[i];
    #pragma unroll
    for (int off = 32; off > 0; off >>= 1)
        a += __shfl_down(a, off, 64);
    __shared__ double wsum[4];
    int lane = tid & 63, wid = tid >> 6;
    if (lane == 0) wsum[wid] = a;
    __syncthreads();
    if (tid == 0) out[0] = (float)(wsum[0] + wsum[1] + wsum[2] + wsum[3]);
}

extern "C" void kernel_launch(void* const* d_in, const int* in_sizes, int n_in,
                              void* d_out, int out_size, void* d_ws, size_t ws_size,
                              hipStream_t stream)
{
    const float* verts = (const float*)d_in[0];
    const int*   faces = (const int*)d_in[1];
    const float* Kmat  = (const float*)d_in[2];
    const float* Rmat  = (const float*)d_in[3];
    const float* tvec  = (const float*)d_in[4];
    const float* texin = (const float*)d_in[5];
    const float* imref = (const float*)d_in[6];

    int B = in_sizes[2] / 9;                    // K is (B,3,3)
    int V = in_sizes[0] / (3 * B);
    int F = in_sizes[1] / (3 * B);
    long ss = in_sizes[6] / (3L * B);           // image_ref is (B,3,S,S)
    int S = (int)(sqrt((double)ss) + 0.5);

    char* ws = (char*)d_ws;
    double* partials = (double*)ws;                                  // <=8 KB
    float4* vdat   = (float4*)(ws + 8192);                           // B*V*16
    float4* finner = (float4*)(ws + 8192 + (size_t)B*V*16);          // B*F*48
    float4* fepi   = (float4*)((char*)finner + (size_t)B*F*48);      // B*F*48
    float*  texd   = (float*)((char*)fepi + (size_t)B*F*48);         // F*96

    int npre = B*V + F*24;
    k_pre<<<(npre + 255)/256, 256, 0, stream>>>(verts, Kmat, Rmat, tvec, texin,
                                                vdat, texd, B, V, F, S);
    k_face<<<(B*F + 255)/256, 256, 0, stream>>>(faces, vdat, finner, fepi, B, V, F);
    int npix = B * S * S;
    int nblk = npix / 256;
    k_raster<<<nblk, 256, 0, stream>>>(finner, fepi, texd, imref, partials, B, F, S);
    k_final<<<1, 256, 0, stream>>>(partials, (float*)d_out, nblk);
}

// Round 2
// 123.609 us; speedup vs baseline: 1.9653x; 1.9653x over previous
//
#include <hip/hip_runtime.h>
#include <math.h>

// Differentiable-rasterizer forward: scalar sum((render - ref)^2).
// B=2, V=512, F=768, S=256 (derived from in_sizes at runtime).
//
// R2 changes vs R1 (which was latency-bound: 512 blocks = 2 waves/SIMD,
// VALUBusy 21%):
//  - face-split x4: grid 512 -> 2048 blocks (8 blocks/CU, full occupancy);
//    chunks merge via atomicMax on packed u64 (izbits<<32)|~idx  -> exact
//    argmin-first-tie semantics.
//  - LDS staging of each 192-face coefficient chunk (9 KB) -> broadcast
//    ds_read_b128 in the inner loop instead of global loads.
//  - prologue fused into one single-block kernel (verts staged in LDS).

#define NCHUNK 4
#define MAXFC  256   // max faces per chunk (F <= 1024)

__global__ __launch_bounds__(1024)
void k_prep(const float* __restrict__ verts, const int* __restrict__ faces,
            const float* __restrict__ Kmat, const float* __restrict__ Rmat,
            const float* __restrict__ tvec, const float* __restrict__ texin,
            float4* __restrict__ finner, float4* __restrict__ fepi,
            float* __restrict__ texd, int B, int V, int F, int S)
{
    __shared__ float4 svdat[2048];          // B*V <= 2048 (here 1024)
    int tid = threadIdx.x;
    // tanh(textures)
    for (int j = tid; j < F * 24; j += 1024) texd[j] = tanhf(texin[j]);
    // project vertices -> NDC (u,v) + cam z
    int nv = B * V;
    for (int i = tid; i < nv; i += 1024) {
        int b = i / V;
        const float* vp = verts + (size_t)i * 3;
        float vx = vp[0], vy = vp[1], vz = vp[2];
        const float* R  = Rmat + b * 9;
        const float* Kb = Kmat + b * 9;
        const float* tb = tvec + b * 3;
        float c0 = R[0]*vx + R[1]*vy + R[2]*vz + tb[0];
        float c1 = R[3]*vx + R[4]*vy + R[5]*vz + tb[1];
        float c2 = R[6]*vx + R[7]*vy + R[8]*vz + tb[2];
        float z  = c2;
        float zd = z + 1e-9f;
        float xh = c0 / zd;
        float yh = c1 / zd;
        float p0 = xh*Kb[0] + yh*Kb[1] + Kb[2];
        float p1 = xh*Kb[3] + yh*Kb[4] + Kb[5];
        float Sf = (float)S;
        float u = 2.0f * (p0 - 0.5f*Sf) / Sf;
        float v = 2.0f * ((Sf - p1) - 0.5f*Sf) / Sf;
        svdat[i] = make_float4(u, v, z, 0.0f);
    }
    __syncthreads();
    // per-face affine coefficients + epilogue data
    int nf = B * F;
    for (int i = tid; i < nf; i += 1024) {
        int b = i / F;
        const int* fp = faces + (size_t)i * 3;
        float4 p0 = svdat[b*V + fp[0]];
        float4 p1 = svdat[b*V + fp[1]];
        float4 p2 = svdat[b*V + fp[2]];
        float x0 = p0.x, y0 = p0.y, z0 = p0.z;
        float x1 = p1.x, y1 = p1.y, z1 = p1.z;
        float x2 = p2.x, y2 = p2.y, z2 = p2.z;
        float e1x = x1 - x0, e1y = y1 - y0;
        float e2x = x2 - x0, e2y = y2 - y0;
        float den = e1x*e2y - e2x*e1y;
        bool valid = fabsf(den) > 1e-8f;
        float dens = valid ? den : 1.0f;
        bool front = fminf(z0, fminf(z1, z2)) > 1e-9f;
        bool ok = valid && front;
        float A1 = e2y / dens, B1 = -e2x / dens;
        float C1 = -(x0*A1 + y0*B1);
        float A2 = -e1y / dens, B2 = e1x / dens;
        float C2 = -(x0*A2 + y0*B2);
        float A0 = -A1 - A2, B0 = -B1 - B2, C0 = 1.0f - C1 - C2;
        float rz0 = 1.0f/z0, rz1 = 1.0f/z1, rz2 = 1.0f/z2;
        float Az = A0*rz0 + A1*rz1 + A2*rz2;
        float Bz = B0*rz0 + B1*rz1 + B2*rz2;
        float Cz = C0*rz0 + C1*rz1 + C2*rz2;
        if (!ok) {
            A0 = B0 = 0.0f; C0 = -1.0f;
            A1 = B1 = C1 = 0.0f;
            A2 = B2 = C2 = 0.0f;
            Az = Bz = Cz = 0.0f;
        }
        finner[(size_t)i*3 + 0] = make_float4(A0, A1, A2, Az);
        finner[(size_t)i*3 + 1] = make_float4(B0, B1, B2, Bz);
        finner[(size_t)i*3 + 2] = make_float4(C0, C1, C2, Cz);
        fepi[(size_t)i*3 + 0] = make_float4(x0, y0, z0, z1);
        fepi[(size_t)i*3 + 1] = make_float4(z2, e1x, e1y, e2x);
        fepi[(size_t)i*3 + 2] = make_float4(e2y, dens, 0.0f, 0.0f);
    }
}

__global__ __launch_bounds__(256, 8)
void k_raster(const float4* __restrict__ finner,
              unsigned long long* __restrict__ cres, int B, int F, int S)
{
    __shared__ float4 sf[MAXFC * 3];       // 12 KB
    int tid = threadIdx.x;
    int pb  = blockIdx.x >> 2;             // pixel block (256 px each)
    int c   = blockIdx.x & (NCHUNK - 1);   // face chunk
    int Fc  = (F + NCHUNK - 1) / NCHUNK;
    int f0  = c * Fc;
    int f1  = min(F, f0 + Fc);
    int p   = pb * 256 + tid;
    int SS  = S * S;
    int b   = p / SS;
    int rem = p - b * SS;
    int py  = rem / S;
    int px  = rem - py * S;
    float Sf  = (float)S;
    float pxf = (2.0f*px + 1.0f - Sf) / Sf;
    float pyf = (2.0f*py + 1.0f - Sf) / Sf;

    // stage this chunk's coefficients into LDS (sentinel-pad: C0 = -1)
    int n3 = (f1 - f0) * 3;
    const float4* src = finner + ((size_t)b * F + f0) * 3;
    for (int k = tid; k < Fc * 3; k += 256) {
        float4 v = make_float4(0.0f, 0.0f, 0.0f, 0.0f);
        if (k < n3)          v = src[k];
        else if (k % 3 == 2) v.x = -1.0f;   // sentinel face: w0 < 0 always
        sf[k] = v;
    }
    __syncthreads();

    float best = 1e-9f;    // invz > EPS gate
    int   bidx = f0;
    #pragma unroll 4
    for (int j = 0; j < Fc; ++j) {
        float4 Av = sf[j*3 + 0];           // broadcast ds_read_b128
        float4 Bv = sf[j*3 + 1];
        float4 Cv = sf[j*3 + 2];
        float w0 = fmaf(pxf, Av.x, fmaf(pyf, Bv.x, Cv.x));
        float w1 = fmaf(pxf, Av.y, fmaf(pyf, Bv.y, Cv.y));
        float w2 = fmaf(pxf, Av.z, fmaf(pyf, Bv.z, Cv.z));
        float iz = fmaf(pxf, Av.w, fmaf(pyf, Bv.w, Cv.w));
        float mn = fminf(w0, fminf(w1, w2));
        bool upd = (mn >= 0.0f) && (iz > best);  // strict > == first-max kept
        best = upd ? iz : best;
        bidx = upd ? f0 + j : bidx;
    }
    // pack (iz, ~idx): higher iz wins; equal iz -> lower face idx wins.
    unsigned long long pk =
        ((unsigned long long)__float_as_uint(best) << 32) |
        (unsigned long long)(~(unsigned int)bidx);
    atomicMax(&cres[p], pk);
}

__global__ __launch_bounds__(256)
void k_merge(const unsigned long long* __restrict__ cres,
             const float4* __restrict__ fepi, const float* __restrict__ texd,
             const float* __restrict__ imref, double* __restrict__ partials,
             int B, int F, int S)
{
    int tid = threadIdx.x;
    int p   = blockIdx.x * 256 + tid;
    int SS  = S * S;
    int b   = p / SS;
    int rem = p - b * SS;
    int py  = rem / S;
    int px  = rem - py * S;
    float Sf  = (float)S;
    float pxf = (2.0f*px + 1.0f - Sf) / Sf;
    float pyf = (2.0f*py + 1.0f - Sf) / Sf;

    unsigned long long pk = cres[p];
    float best = __uint_as_float((unsigned int)(pk >> 32));
    int   bidx = (int)(~(unsigned int)pk);
    bool  hit  = best > 1e-9f;
    if (!hit) bidx = 0;                    // all-miss: argmin of all-inf = 0

    const float4* fe = fepi + (size_t)(b*F + bidx) * 3;
    float4 e0 = fe[0], e1 = fe[1], e2 = fe[2];
    float X0 = e0.x, Y0 = e0.y, Z0 = e0.z, Z1 = e0.w;
    float Z2 = e1.x, E1x = e1.y, E1y = e1.z, E2x = e1.w;
    float E2y = e2.x, D = e2.y;
    float dxp = pxf - X0, dyp = pyf - Y0;
    float W1 = (dxp*E2y - dyp*E2x) / D;
    float W2 = (E1x*dyp - E1y*dxp) / D;
    float W0 = 1.0f - W1 - W2;
    float q0 = W0 / Z0, q1 = W1 / Z1, q2 = W2 / Z2;
    float iz = fmaxf(q0 + q1 + q2, 1e-9f);
    float wp0 = fminf(fmaxf(q0 / iz, 0.0f), 1.0f);
    float wp1 = fminf(fmaxf(q1 / iz, 0.0f), 1.0f);
    float wp2 = fminf(fmaxf(q2 / iz, 0.0f), 1.0f);
    const float* T = texd + (size_t)bidx * 24;
    float hitf = hit ? 1.0f : 0.0f;
    float a0l = 1.0f - wp0, a0h = wp0;
    float a1l = 1.0f - wp1, a1h = wp1;
    float a2l = 1.0f - wp2, a2h = wp2;
    float s = 0.0f;
    #pragma unroll
    for (int cc = 0; cc < 3; ++cc) {
        float col =
            a0l*(a1l*(a2l*T[0  + cc] + a2h*T[3  + cc]) + a1h*(a2l*T[6  + cc] + a2h*T[9  + cc])) +
            a0h*(a1l*(a2l*T[12 + cc] + a2h*T[15 + cc]) + a1h*(a2l*T[18 + cc] + a2h*T[21 + cc]));
        col *= hitf;
        float r = imref[(((size_t)b*3 + cc)*S + py)*S + px];
        float d = col - r;
        s = fmaf(d, d, s);
    }

    double acc = (double)s;
    #pragma unroll
    for (int off = 32; off > 0; off >>= 1)
        acc += __shfl_down(acc, off, 64);
    __shared__ double wsum[4];
    int lane = tid & 63, wid = tid >> 6;
    if (lane == 0) wsum[wid] = acc;
    __syncthreads();
    if (tid == 0) partials[blockIdx.x] = wsum[0] + wsum[1] + wsum[2] + wsum[3];
}

__global__ void k_final(const double* __restrict__ partials, float* __restrict__ out, int n)
{
    int tid = threadIdx.x;
    double a = 0.0;
    for (int i = tid; i < n; i += 256) a += partials[i];
    #pragma unroll
    for (int off = 32; off > 0; off >>= 1)
        a += __shfl_down(a, off, 64);
    __shared__ double wsum[4];
    int lane = tid & 63, wid = tid >> 6;
    if (lane == 0) wsum[wid] = a;
    __syncthreads();
    if (tid == 0) out[0] = (float)(wsum[0] + wsum[1] + wsum[2] + wsum[3]);
}

extern "C" void kernel_launch(void* const* d_in, const int* in_sizes, int n_in,
                              void* d_out, int out_size, void* d_ws, size_t ws_size,
                              hipStream_t stream)
{
    const float* verts = (const float*)d_in[0];
    const int*   faces = (const int*)d_in[1];
    const float* Kmat  = (const float*)d_in[2];
    const float* Rmat  = (const float*)d_in[3];
    const float* tvec  = (const float*)d_in[4];
    const float* texin = (const float*)d_in[5];
    const float* imref = (const float*)d_in[6];

    int B = in_sizes[2] / 9;                    // K is (B,3,3)
    int V = in_sizes[0] / (3 * B);
    int F = in_sizes[1] / (3 * B);
    long ss = in_sizes[6] / (3L * B);           // image_ref is (B,3,S,S)
    int S = (int)(sqrt((double)ss) + 0.5);
    int npix = B * S * S;

    char* ws = (char*)d_ws;
    double* partials = (double*)ws;                                  // 8 KB
    float4* finner = (float4*)(ws + 8192);                           // B*F*48
    float4* fepi   = (float4*)((char*)finner + (size_t)B*F*48);      // B*F*48
    float*  texd   = (float*)((char*)fepi + (size_t)B*F*48);         // F*96
    size_t  texd_b = ((size_t)F*96 + 15) & ~(size_t)15;
    unsigned long long* cres = (unsigned long long*)((char*)texd + texd_b);  // npix*8

    hipMemsetAsync(cres, 0, (size_t)npix * 8, stream);
    k_prep<<<1, 1024, 0, stream>>>(verts, faces, Kmat, Rmat, tvec, texin,
                                   finner, fepi, texd, B, V, F, S);
    int npixblk = npix / 256;
    k_raster<<<npixblk * NCHUNK, 256, 0, stream>>>(finner, cres, B, F, S);
    k_merge<<<npixblk, 256, 0, stream>>>(cres, fepi, texd, imref, partials, B, F, S);
    k_final<<<1, 256, 0, stream>>>(partials, (float*)d_out, npixblk);
}